// Round 1
// baseline (6037.924 us; speedup 1.0000x reference)
//
#include <hip/hip_runtime.h>

#define HH 128
#define WW 128

__device__ __forceinline__ float hsig(float x) {
    float t = fmaf(0.2f, x, 0.5f);
    return fminf(fmaxf(t, 0.f), 1.f);
}

// One ConvLSTM step for one layer.
// xin: [B][H][W][CIN] with per-batch stride xbs (elements)
// res: optional residual added to xin before relu (mode 2), [B][H][W][32]
// Wx: [3][3][CIN][128], Wh: [3][3][32][128], bias: [128]
// hprev/cst/hout: [B][H][W][32]
// mode: 0 = raw input, 1 = relu(x), 2 = relu(x + res)
template<int CIN>
__global__ __launch_bounds__(256)
void lstm_step(const float* __restrict__ xin, size_t xbs,
               const float* __restrict__ res,
               const float* __restrict__ Wx,
               const float* __restrict__ Wh,
               const float* __restrict__ bias,
               const float* __restrict__ hprev,
               float* __restrict__ cst,
               float* __restrict__ hout,
               const int mode)
{
    __shared__ float sx[CIN * 101];   // [cin][pix], stride 101 (odd -> conflict-free)
    __shared__ float sh[32 * 101];
    __shared__ float swx[CIN * 128];  // one tap: [cin][cout]
    __shared__ float swh[32 * 128];

    const int tid = threadIdx.x;
    const int bx = blockIdx.x, by = blockIdx.y, bb = blockIdx.z;
    const int x0 = bx * 8 - 1, y0 = by * 8 - 1;  // halo origin

    // ---- stage input tile (10x10 halo, zero SAME padding) ----
    for (int idx = tid; idx < 100 * CIN; idx += 256) {
        const int pix = idx / CIN;
        const int ci  = idx - pix * CIN;
        const int ry  = pix / 10;
        const int rx  = pix - ry * 10;
        const int gy = y0 + ry, gx = x0 + rx;
        float v = 0.f;
        if ((unsigned)gy < HH && (unsigned)gx < WW) {
            v = xin[(size_t)bb * xbs + ((size_t)gy * WW + gx) * CIN + ci];
            if (mode == 1) {
                v = fmaxf(v, 0.f);
            } else if (mode == 2) {
                v += res[(((size_t)bb * HH + gy) * WW + gx) * 32 + ci];
                v = fmaxf(v, 0.f);
            }
        }
        sx[ci * 101 + pix] = v;
    }
    // ---- stage hprev tile ----
    for (int idx = tid; idx < 100 * 32; idx += 256) {
        const int pix = idx >> 5;
        const int ci  = idx & 31;
        const int ry  = pix / 10;
        const int rx  = pix - ry * 10;
        const int gy = y0 + ry, gx = x0 + rx;
        float v = 0.f;
        if ((unsigned)gy < HH && (unsigned)gx < WW)
            v = hprev[(((size_t)bb * HH + gy) * WW + gx) * 32 + ci];
        sh[ci * 101 + pix] = v;
    }

    const int pix = tid >> 2;     // 0..63 : 8x8 output pixels
    const int cg  = tid & 3;      // 0..3  : channel group (8 filters each)
    const int py  = pix >> 3, px = pix & 7;
    const int cbase = cg * 8;

    float acc[4][8];  // [gate i,f,g,o][filter]
    #pragma unroll
    for (int g = 0; g < 4; ++g)
        #pragma unroll
        for (int j = 0; j < 8; ++j)
            acc[g][j] = bias[g * 32 + cbase + j];

    for (int tap = 0; tap < 9; ++tap) {
        __syncthreads();   // previous tap's weights fully consumed
        for (int idx = tid; idx < CIN * 128; idx += 256)
            swx[idx] = Wx[tap * CIN * 128 + idx];
        for (int idx = tid; idx < 32 * 128; idx += 256)
            swh[idx] = Wh[tap * 32 * 128 + idx];
        __syncthreads();   // weights (and, on tap 0, input tiles) ready

        const int dy = tap / 3, dx = tap - dy * 3;
        const int lp = (py + dy) * 10 + (px + dx);

        for (int ci = 0; ci < CIN; ++ci) {
            const float xv = sx[ci * 101 + lp];
            const float4* wp = (const float4*)(swx + ci * 128 + cbase);
            #pragma unroll
            for (int g = 0; g < 4; ++g) {
                const float4 w0 = wp[g * 8];
                const float4 w1 = wp[g * 8 + 1];
                acc[g][0] = fmaf(xv, w0.x, acc[g][0]);
                acc[g][1] = fmaf(xv, w0.y, acc[g][1]);
                acc[g][2] = fmaf(xv, w0.z, acc[g][2]);
                acc[g][3] = fmaf(xv, w0.w, acc[g][3]);
                acc[g][4] = fmaf(xv, w1.x, acc[g][4]);
                acc[g][5] = fmaf(xv, w1.y, acc[g][5]);
                acc[g][6] = fmaf(xv, w1.z, acc[g][6]);
                acc[g][7] = fmaf(xv, w1.w, acc[g][7]);
            }
        }
        for (int ci = 0; ci < 32; ++ci) {
            const float hv = sh[ci * 101 + lp];
            const float4* wp = (const float4*)(swh + ci * 128 + cbase);
            #pragma unroll
            for (int g = 0; g < 4; ++g) {
                const float4 w0 = wp[g * 8];
                const float4 w1 = wp[g * 8 + 1];
                acc[g][0] = fmaf(hv, w0.x, acc[g][0]);
                acc[g][1] = fmaf(hv, w0.y, acc[g][1]);
                acc[g][2] = fmaf(hv, w0.z, acc[g][2]);
                acc[g][3] = fmaf(hv, w0.w, acc[g][3]);
                acc[g][4] = fmaf(hv, w1.x, acc[g][4]);
                acc[g][5] = fmaf(hv, w1.y, acc[g][5]);
                acc[g][6] = fmaf(hv, w1.z, acc[g][6]);
                acc[g][7] = fmaf(hv, w1.w, acc[g][7]);
            }
        }
    }

    // ---- gates + state update ----
    const int gy = by * 8 + py, gx = bx * 8 + px;
    const size_t base = (((size_t)bb * HH + gy) * WW + gx) * 32 + cbase;
    const float4 c0 = *(const float4*)(cst + base);
    const float4 c1 = *(const float4*)(cst + base + 4);
    const float cold[8] = {c0.x, c0.y, c0.z, c0.w, c1.x, c1.y, c1.z, c1.w};
    float cn[8], hn[8];
    #pragma unroll
    for (int j = 0; j < 8; ++j) {
        const float ig = hsig(acc[0][j]);
        const float fg = hsig(acc[1][j]);
        const float gg = tanhf(acc[2][j]);
        const float og = hsig(acc[3][j]);
        const float c2 = fmaf(fg, cold[j], ig * gg);
        cn[j] = c2;
        hn[j] = og * tanhf(c2);
    }
    *(float4*)(cst + base)     = make_float4(cn[0], cn[1], cn[2], cn[3]);
    *(float4*)(cst + base + 4) = make_float4(cn[4], cn[5], cn[6], cn[7]);
    *(float4*)(hout + base)     = make_float4(hn[0], hn[1], hn[2], hn[3]);
    *(float4*)(hout + base + 4) = make_float4(hn[4], hn[5], hn[6], hn[7]);
}

extern "C" void kernel_launch(void* const* d_in, const int* in_sizes, int n_in,
                              void* d_out, int out_size, void* d_ws, size_t ws_size,
                              hipStream_t stream) {
    const float* x = (const float*)d_in[0];
    const float* Wx[4] = {(const float*)d_in[1], (const float*)d_in[4],
                          (const float*)d_in[7], (const float*)d_in[10]};
    const float* Wh[4] = {(const float*)d_in[2], (const float*)d_in[5],
                          (const float*)d_in[8], (const float*)d_in[11]};
    const float* bs[4] = {(const float*)d_in[3], (const float*)d_in[6],
                          (const float*)d_in[9], (const float*)d_in[12]};
    float* out = (float*)d_out;

    const size_t S  = (size_t)4 * HH * WW * 32;   // one [B,H,W,32] buffer (elements)
    const size_t HB = (size_t)HH * WW * 32;       // per-batch stride of h buffers

    float* ws = (float*)d_ws;
    float* hA[4]; float* hB[4]; float* cs[4];
    for (int l = 0; l < 4; ++l) {
        hA[l] = ws + (size_t)(3 * l + 0) * S;
        hB[l] = ws + (size_t)(3 * l + 1) * S;
        cs[l] = ws + (size_t)(3 * l + 2) * S;
    }
    // h0 = c0 = 0 for every layer, re-done every call (deterministic)
    for (int l = 0; l < 4; ++l) {
        hipMemsetAsync(hA[l], 0, S * sizeof(float), stream);
        hipMemsetAsync(cs[l], 0, S * sizeof(float), stream);
    }

    dim3 grid(WW / 8, HH / 8, 4);
    dim3 blk(256);

    float* hp[4] = {hA[0], hA[1], hA[2], hA[3]};
    float* hc[4] = {hB[0], hB[1], hB[2], hB[3]};

    for (int t = 0; t < 8; ++t) {
        // layer 0: input x[:, t]   (Cin = 16)
        lstm_step<16><<<grid, blk, 0, stream>>>(
            x + (size_t)t * HH * WW * 16, (size_t)8 * HH * WW * 16, nullptr,
            Wx[0], Wh[0], bs[0], hp[0], cs[0], hc[0], 0);
        // layer 1: input y0[t] raw
        lstm_step<32><<<grid, blk, 0, stream>>>(
            hc[0], HB, nullptr,
            Wx[1], Wh[1], bs[1], hp[1], cs[1], hc[1], 0);
        // layer 2: input relu(y1[t])
        lstm_step<32><<<grid, blk, 0, stream>>>(
            hc[1], HB, nullptr,
            Wx[2], Wh[2], bs[2], hp[2], cs[2], hc[2], 1);
        // layer 3: input relu(y2[t] + y0[t]); last step writes d_out
        lstm_step<32><<<grid, blk, 0, stream>>>(
            hc[2], HB, hc[0],
            Wx[3], Wh[3], bs[3], hp[3], cs[3], (t == 7) ? out : hc[3], 2);

        for (int l = 0; l < 4; ++l) { float* tmp = hp[l]; hp[l] = hc[l]; hc[l] = tmp; }
    }
}

// Round 2
// 3627.841 us; speedup vs baseline: 1.6643x; 1.6643x over previous
//
#include <hip/hip_runtime.h>

#define HH 128
#define WW 128

typedef float f32x4 __attribute__((ext_vector_type(4)));
typedef float f32x8 __attribute__((ext_vector_type(8)));

__device__ __forceinline__ float hsig(float x) {
    return fminf(fmaxf(fmaf(0.2f, x, 0.5f), 0.f), 1.f);
}

// One ConvLSTM step, one layer.
// Mapping: block = 8x8 pixel tile x batch; wave = filter-group cg (8 filters,
// all 4 gates); lane = pixel. Weights are wave-uniform -> scalar (SGPR) loads.
// LDS holds only activation tiles; ONE barrier per kernel, tap loop barrier-free.
template<int CIN>
__global__ __launch_bounds__(256)
void lstm_step(const float* __restrict__ xin, size_t xbs,
               const float* __restrict__ res,
               const float* __restrict__ Wx,
               const float* __restrict__ Wh,
               const float* __restrict__ bias,
               const float* __restrict__ hprev,
               float* __restrict__ cst,
               float* __restrict__ hout,
               const int mode)   // 0 raw, 1 relu(x), 2 relu(x+res)
{
    constexpr int ST = 125;           // channel-plane stride (10 rows x 12 + 5 pad)
    __shared__ float sx[CIN * ST];    // [ci][ry*12+rx]
    __shared__ float sh[32 * ST];

    const int tid = threadIdx.x;
    const int bx = blockIdx.x, by = blockIdx.y, bb = blockIdx.z;
    const int x0 = bx * 8 - 1, y0 = by * 8 - 1;   // halo origin

    // ---- stage x halo tile (10x10), float4 loads, transpose to [ci][pix] ----
    for (int i = tid; i < 100 * (CIN / 4); i += 256) {
        const int pix = i / (CIN / 4);
        const int c4  = i - pix * (CIN / 4);
        const int ry = pix / 10, rx = pix - ry * 10;
        const int gy = y0 + ry, gx = x0 + rx;
        f32x4 v = {0.f, 0.f, 0.f, 0.f};
        if ((unsigned)gy < HH && (unsigned)gx < WW) {
            v = *(const f32x4*)(xin + (size_t)bb * xbs + ((size_t)gy * WW + gx) * CIN + c4 * 4);
            if (mode == 2) {
                f32x4 r = *(const f32x4*)(res + (((size_t)bb * HH + gy) * WW + gx) * 32 + c4 * 4);
                v.x += r.x; v.y += r.y; v.z += r.z; v.w += r.w;
            }
            if (mode != 0) {
                v.x = fmaxf(v.x, 0.f); v.y = fmaxf(v.y, 0.f);
                v.z = fmaxf(v.z, 0.f); v.w = fmaxf(v.w, 0.f);
            }
        }
        const int off = ry * 12 + rx;
        sx[(c4 * 4 + 0) * ST + off] = v.x;
        sx[(c4 * 4 + 1) * ST + off] = v.y;
        sx[(c4 * 4 + 2) * ST + off] = v.z;
        sx[(c4 * 4 + 3) * ST + off] = v.w;
    }
    // ---- stage hprev halo tile ----
    for (int i = tid; i < 100 * 8; i += 256) {
        const int pix = i >> 3;
        const int c4  = i & 7;
        const int ry = pix / 10, rx = pix - ry * 10;
        const int gy = y0 + ry, gx = x0 + rx;
        f32x4 v = {0.f, 0.f, 0.f, 0.f};
        if ((unsigned)gy < HH && (unsigned)gx < WW)
            v = *(const f32x4*)(hprev + (((size_t)bb * HH + gy) * WW + gx) * 32 + c4 * 4);
        const int off = ry * 12 + rx;
        sh[(c4 * 4 + 0) * ST + off] = v.x;
        sh[(c4 * 4 + 1) * ST + off] = v.y;
        sh[(c4 * 4 + 2) * ST + off] = v.z;
        sh[(c4 * 4 + 3) * ST + off] = v.w;
    }
    __syncthreads();   // the only barrier

    const int lane = tid & 63;
    // wave-uniform filter-group offset, forced into SGPR
    const int cg8 = __builtin_amdgcn_readfirstlane((tid >> 6) * 8);
    const int py = lane >> 3, px = lane & 7;

    float acc[4][8];   // [gate i,f,g,o][filter]
    #pragma unroll
    for (int g = 0; g < 4; ++g) {
        const f32x8 b = *(const f32x8*)(bias + g * 32 + cg8);
        #pragma unroll
        for (int j = 0; j < 8; ++j) acc[g][j] = b[j];
    }

    for (int tap = 0; tap < 9; ++tap) {
        const int dy = tap / 3, dx = tap - dy * 3;
        const int lp = (py + dy) * 12 + (px + dx);

        const float* __restrict__ wx = Wx + (size_t)tap * CIN * 128 + cg8;
        #pragma unroll 4
        for (int ci = 0; ci < CIN; ++ci) {
            const float xv = sx[ci * ST + lp];
            #pragma unroll
            for (int g = 0; g < 4; ++g) {
                const f32x8 w = *(const f32x8*)(wx + ci * 128 + g * 32);  // uniform -> s_load
                #pragma unroll
                for (int j = 0; j < 8; ++j)
                    acc[g][j] = fmaf(xv, w[j], acc[g][j]);
            }
        }
        const float* __restrict__ wh = Wh + (size_t)tap * 32 * 128 + cg8;
        #pragma unroll 4
        for (int ci = 0; ci < 32; ++ci) {
            const float hv = sh[ci * ST + lp];
            #pragma unroll
            for (int g = 0; g < 4; ++g) {
                const f32x8 w = *(const f32x8*)(wh + ci * 128 + g * 32);
                #pragma unroll
                for (int j = 0; j < 8; ++j)
                    acc[g][j] = fmaf(hv, w[j], acc[g][j]);
            }
        }
    }

    // ---- gates + state update ----
    const int gy = by * 8 + py, gx = bx * 8 + px;
    const size_t base = (((size_t)bb * HH + gy) * WW + gx) * 32 + cg8;
    const f32x4 c0 = *(const f32x4*)(cst + base);
    const f32x4 c1 = *(const f32x4*)(cst + base + 4);
    const float cold[8] = {c0.x, c0.y, c0.z, c0.w, c1.x, c1.y, c1.z, c1.w};
    float cn[8], hn[8];
    #pragma unroll
    for (int j = 0; j < 8; ++j) {
        const float ig = hsig(acc[0][j]);
        const float fg = hsig(acc[1][j]);
        const float gg = tanhf(acc[2][j]);
        const float og = hsig(acc[3][j]);
        const float c2 = fmaf(fg, cold[j], ig * gg);
        cn[j] = c2;
        hn[j] = og * tanhf(c2);
    }
    *(f32x4*)(cst + base)     = (f32x4){cn[0], cn[1], cn[2], cn[3]};
    *(f32x4*)(cst + base + 4) = (f32x4){cn[4], cn[5], cn[6], cn[7]};
    *(f32x4*)(hout + base)     = (f32x4){hn[0], hn[1], hn[2], hn[3]};
    *(f32x4*)(hout + base + 4) = (f32x4){hn[4], hn[5], hn[6], hn[7]};
}

extern "C" void kernel_launch(void* const* d_in, const int* in_sizes, int n_in,
                              void* d_out, int out_size, void* d_ws, size_t ws_size,
                              hipStream_t stream) {
    const float* x = (const float*)d_in[0];
    const float* Wx[4] = {(const float*)d_in[1], (const float*)d_in[4],
                          (const float*)d_in[7], (const float*)d_in[10]};
    const float* Wh[4] = {(const float*)d_in[2], (const float*)d_in[5],
                          (const float*)d_in[8], (const float*)d_in[11]};
    const float* bs[4] = {(const float*)d_in[3], (const float*)d_in[6],
                          (const float*)d_in[9], (const float*)d_in[12]};
    float* out = (float*)d_out;

    const size_t S  = (size_t)4 * HH * WW * 32;   // one [B,H,W,32] buffer (elements)
    const size_t HB = (size_t)HH * WW * 32;       // per-batch stride of h buffers

    float* ws = (float*)d_ws;
    float* hA[4]; float* hB[4]; float* cs[4];
    for (int l = 0; l < 4; ++l) {
        hA[l] = ws + (size_t)(3 * l + 0) * S;
        hB[l] = ws + (size_t)(3 * l + 1) * S;
        cs[l] = ws + (size_t)(3 * l + 2) * S;
    }
    for (int l = 0; l < 4; ++l) {
        hipMemsetAsync(hA[l], 0, S * sizeof(float), stream);
        hipMemsetAsync(cs[l], 0, S * sizeof(float), stream);
    }

    dim3 grid(WW / 8, HH / 8, 4);
    dim3 blk(256);

    float* hp[4] = {hA[0], hA[1], hA[2], hA[3]};
    float* hc[4] = {hB[0], hB[1], hB[2], hB[3]};

    for (int t = 0; t < 8; ++t) {
        lstm_step<16><<<grid, blk, 0, stream>>>(
            x + (size_t)t * HH * WW * 16, (size_t)8 * HH * WW * 16, nullptr,
            Wx[0], Wh[0], bs[0], hp[0], cs[0], hc[0], 0);
        lstm_step<32><<<grid, blk, 0, stream>>>(
            hc[0], HB, nullptr,
            Wx[1], Wh[1], bs[1], hp[1], cs[1], hc[1], 0);
        lstm_step<32><<<grid, blk, 0, stream>>>(
            hc[1], HB, nullptr,
            Wx[2], Wh[2], bs[2], hp[2], cs[2], hc[2], 1);
        lstm_step<32><<<grid, blk, 0, stream>>>(
            hc[2], HB, hc[0],
            Wx[3], Wh[3], bs[3], hp[3], cs[3], (t == 7) ? out : hc[3], 2);

        for (int l = 0; l < 4; ++l) { float* tmp = hp[l]; hp[l] = hc[l]; hc[l] = tmp; }
    }
}